// Round 8
// baseline (156.464 us; speedup 1.0000x reference)
//
#include <hip/hip_runtime.h>
#include <hip/hip_bf16.h>

// Problem constants (B=2, T=4096, D=1024, H=16, HD=64, W=16)
#define D_MODEL 1024
#define SEQ_T   4096
#define NBATCH  2
#define NHEADS  16
#define HEAD_D  64
#define WIN     16

typedef __attribute__((ext_vector_type(8))) short bf16x8;           // MFMA A/B frag
typedef __attribute__((ext_vector_type(8))) unsigned short u16x8;   // 16B bf16 load
typedef __attribute__((ext_vector_type(4))) float f32x4;            // MFMA C/D frag

__device__ __forceinline__ unsigned short f2bf(float f) {
  union { float f; unsigned int u; } v; v.f = f;
  unsigned int r = v.u + 0x7fffu + ((v.u >> 16) & 1u);  // RNE
  return (unsigned short)(r >> 16);
}
__device__ __forceinline__ float bf2f(unsigned short u) {
  union { unsigned int u; float f; } v; v.u = ((unsigned int)u) << 16;
  return v.f;
}

#define SBAR() __builtin_amdgcn_s_barrier()
#define LGKM0() asm volatile("s_waitcnt lgkmcnt(0)" ::: "memory")
#define LGKM8() asm volatile("s_waitcnt lgkmcnt(8)" ::: "memory")
#define VMC(n) asm volatile("s_waitcnt vmcnt(" #n ")" ::: "memory")

// ---------------------------------------------------------------- casts
__global__ __launch_bounds__(256) void cast_f32_bf16(const float4* __restrict__ src,
                                                     ushort* __restrict__ dst, int n4) {
  int i = blockIdx.x * 256 + threadIdx.x;
  if (i >= n4) return;
  float4 v = src[i];
  ushort4 o;
  o.x = f2bf(v.x); o.y = f2bf(v.y); o.z = f2bf(v.z); o.w = f2bf(v.w);
  *(ushort4*)(dst + (size_t)i * 4) = o;
}

// weight cast + HEAD-MAJOR reorder of [wq;wkv]:
// wb row n (n<3072): h=n/192, j=n%192; j<64 -> wq[h*64+j]; j<128 -> wkv[h*128+j-64] (k);
// j<192 -> wkv[h*128+64+j-128] (v). Rows 3072..4095 = wo (unreordered, for GEMM2).
__global__ __launch_bounds__(256) void cast_weights(const float4* __restrict__ wq,
                                                    const float4* __restrict__ wkv,
                                                    const float4* __restrict__ wo,
                                                    ushort* __restrict__ dst) {
  int i = blockIdx.x * 256 + threadIdx.x;  // 0..1048575 float4 units
  int n = i >> 8;           // output row (K=1024 -> 256 float4/row)
  int k4 = i & 255;
  const float4* src;
  if (n < 3072) {
    int h = n / 192, j = n % 192;
    if (j < 64) src = wq + ((size_t)(h * 64 + j) << 8) + k4;
    else if (j < 128) src = wkv + ((size_t)(h * 128 + (j - 64)) << 8) + k4;
    else src = wkv + ((size_t)(h * 128 + 64 + (j - 128)) << 8) + k4;
  } else {
    src = wo + ((size_t)(n - 3072) << 8) + k4;
  }
  float4 v = *src;
  ushort4 o;
  o.x = f2bf(v.x); o.y = f2bf(v.y); o.z = f2bf(v.z); o.w = f2bf(v.w);
  *(ushort4*)(dst + (size_t)i * 4) = o;
}

// ---------------------------------------------------------------- boundary k/v pre-GEMM
// For each m-block by (m0=by*256) not at a batch start, compute k,v for rows m0-16..m0-1,
// all heads: bkv[by*16 + r][h*128 + c] (c<64: k, c>=64: v), bf16. 2.1 GF total.
// Block = (by, h), 256 thr = 4 waves; wave wv computes col-frags {2wv, 2wv+1} of 128.
__global__ __launch_bounds__(256) void pre_kv(const ushort* __restrict__ xb,
                                              const ushort* __restrict__ wb,
                                              ushort* __restrict__ bkv) {
  const int by = blockIdx.x;
  const int h = blockIdx.y;
  const int m0 = by * 256;
  if ((m0 & (SEQ_T - 1)) == 0) return;  // batch-start: window rows are masked anyway
  const int tid = threadIdx.x;
  const int wv = tid >> 6;
  const int lane = tid & 63;
  const int fr = lane & 15, g = lane >> 4;

  f32x4 acc2[2];
  acc2[0] = (f32x4){0.f, 0.f, 0.f, 0.f};
  acc2[1] = (f32x4){0.f, 0.f, 0.f, 0.f};
  const ushort* arow = xb + (size_t)(m0 - 16 + fr) * 1024;
  const ushort* b0 = wb + (size_t)(h * 192 + 64 + (wv * 2) * 16 + fr) * 1024;
  const ushort* b1 = wb + (size_t)(h * 192 + 64 + (wv * 2 + 1) * 16 + fr) * 1024;
#pragma unroll 4
  for (int k0 = 0; k0 < 1024; k0 += 32) {
    bf16x8 a = *(const bf16x8*)(arow + k0 + g * 8);
    bf16x8 bb0 = *(const bf16x8*)(b0 + k0 + g * 8);
    bf16x8 bb1 = *(const bf16x8*)(b1 + k0 + g * 8);
    acc2[0] = __builtin_amdgcn_mfma_f32_16x16x32_bf16(a, bb0, acc2[0], 0, 0, 0);
    acc2[1] = __builtin_amdgcn_mfma_f32_16x16x32_bf16(a, bb1, acc2[1], 0, 0, 0);
  }
#pragma unroll
  for (int ci = 0; ci < 2; ++ci)
#pragma unroll
    for (int reg = 0; reg < 4; ++reg)
      bkv[(size_t)(by * 16 + g * 4 + reg) * 2048 + h * 128 + (wv * 2 + ci) * 16 + fr] =
          f2bf(acc2[ci][reg]);
}

// ---------------------------------------------------------------- fused GEMM1 + window attention
// Block (bx=head h, by=m-block): 256 rows x 192 cols = one head's q|k|v for 256 timesteps.
// K-loop: identical 6-phase/2-K-tile schedule as R7 (verified). Epilogue: vmcnt(0) drain,
// then per 128-row half: acc -> LDS (q [128][72], k [144][136], v^T [64][152]; 16 boundary
// rows from bkv for half 0 / from acc rows 112..127 for half 1), band-MFMA attention
// (wave w owns 16 t's: S=Q@K^T 4 MFMA, mask+sigmoid, P via Ps LDS, msg=P@V 4 MFMA),
// msg written straight to global bf16. No qkv buffer ever hits HBM.
__global__ __launch_bounds__(512, 2) void gemm1_fused(const ushort* __restrict__ A,
                                                      const ushort* __restrict__ Bt,
                                                      const ushort* __restrict__ bkv,
                                                      ushort* __restrict__ msg,
                                                      int M, int K) {
  extern __shared__ char smem[];  // 114688 bytes
  const int tid = threadIdx.x;
  const int wid = tid >> 6;
  const int lane = tid & 63;
  const int h = blockIdx.x;
  const int m0 = blockIdx.y * 256;
  const int n0 = h * 192;

  // staging lane geometry (pre-swizzled source chunk; involution c ^= row&7)
  const int l8 = lane >> 3;
  const int lchunk = (lane & 7) ^ (l8 & 7);
  const ushort* pA = A + (size_t)(m0 + wid * 8 + l8) * K + lchunk * 8;
  const ushort* pB = Bt + (size_t)(n0 + wid * 8 + l8) * K + lchunk * 8;

#define SA(kt, db, j0)                                                                     \
  {                                                                                        \
    _Pragma("unroll") for (int j = (j0); j < (j0) + 2; ++j) {                              \
      const ushort* gp = pA + (size_t)(j * 64) * K + (size_t)(kt) * 64;                    \
      char* lp = smem + (db) * 32768 + (j * 8 + wid) * 1024;                               \
      __builtin_amdgcn_global_load_lds((const __attribute__((address_space(1))) void*)gp,  \
                                       (__attribute__((address_space(3))) void*)lp, 16, 0, 0); \
    }                                                                                      \
  }
#define SB(kt, db)                                                                         \
  {                                                                                        \
    _Pragma("unroll") for (int j = 0; j < 3; ++j) {                                        \
      const ushort* gp = pB + (size_t)(j * 64) * K + (size_t)(kt) * 64;                    \
      char* lp = smem + 65536 + (db) * 24576 + (j * 8 + wid) * 1024;                       \
      __builtin_amdgcn_global_load_lds((const __attribute__((address_space(1))) void*)gp,  \
                                       (__attribute__((address_space(3))) void*)lp, 16, 0, 0); \
    }                                                                                      \
  }

  const int fr = lane & 15;
  const int g = lane >> 4;
  const int wr = wid >> 1;   // 0..3
  const int wc = wid & 1;    // 0..1
  int aRow[4], bRow[6], ch[2];
#pragma unroll
  for (int mi = 0; mi < 4; ++mi) aRow[mi] = (wr * 64 + mi * 16 + fr) * 128;
#pragma unroll
  for (int j = 0; j < 6; ++j) bRow[j] = (wc * 96 + j * 16 + fr) * 128;
#pragma unroll
  for (int kk = 0; kk < 2; ++kk) ch[kk] = ((kk * 4 + g) ^ (fr & 7)) * 16;

  f32x4 acc[4][6];
#pragma unroll
  for (int mi = 0; mi < 4; ++mi)
#pragma unroll
    for (int j = 0; j < 6; ++j) acc[mi][j] = (f32x4){0.f, 0.f, 0.f, 0.f};

  bf16x8 a[4][2], b[2][2];

#define RD_A(db)                                                               \
  _Pragma("unroll") for (int mi = 0; mi < 4; ++mi)                             \
    _Pragma("unroll") for (int kk = 0; kk < 2; ++kk)                           \
      a[mi][kk] = *(const bf16x8*)(smem + (db) * 32768 + aRow[mi] + ch[kk]);
#define RD_B(db, nh)                                                           \
  _Pragma("unroll") for (int ni = 0; ni < 2; ++ni)                             \
    _Pragma("unroll") for (int kk = 0; kk < 2; ++kk)                           \
      b[ni][kk] = *(const bf16x8*)(smem + 65536 + (db) * 24576 +               \
                                   bRow[(nh) * 2 + ni] + ch[kk]);
#define MM(nh)                                                                 \
  __builtin_amdgcn_s_setprio(1);                                               \
  _Pragma("unroll") for (int kk = 0; kk < 2; ++kk)                             \
    _Pragma("unroll") for (int mi = 0; mi < 4; ++mi)                           \
      _Pragma("unroll") for (int ni = 0; ni < 2; ++ni)                         \
        acc[mi][(nh) * 2 + ni] = __builtin_amdgcn_mfma_f32_16x16x32_bf16(      \
            a[mi][kk], b[ni][kk], acc[mi][(nh) * 2 + ni], 0, 0, 0);            \
  __builtin_amdgcn_s_setprio(0);

  SA(0, 0, 0); SA(0, 0, 2); SB(0, 0); SA(1, 1, 0); SA(1, 1, 2);
  VMC(4);
  SBAR();

#pragma unroll 1
  for (int i = 0; i < 8; ++i) {
    const int t1 = 2 * i + 1;
    const int t2 = (2 * i + 2 < 16) ? 2 * i + 2 : 15;
    const int t3 = (2 * i + 3 < 16) ? 2 * i + 3 : 15;
    const int d2 = t2 & 1, d3 = t3 & 1;

    RD_A(0); RD_B(0, 0);
    SB(t1, 1);
    LGKM8();
    SBAR(); LGKM0();
    MM(0);
    SBAR();

    RD_B(0, 1);
    SA(t2, d2, 0);
    SBAR(); LGKM0();
    MM(1);
    SBAR();

    RD_B(0, 2);
    SA(t2, d2, 2);
    VMC(4);
    SBAR(); LGKM0();
    MM(2);
    SBAR();

    RD_A(1); RD_B(1, 0);
    SB(t2, d2);
    LGKM8();
    SBAR(); LGKM0();
    MM(0);
    SBAR();

    RD_B(1, 1);
    SA(t3, d3, 0);
    SBAR(); LGKM0();
    MM(1);
    SBAR();

    RD_B(1, 2);
    SA(t3, d3, 2);
    VMC(4);
    SBAR(); LGKM0();
    MM(2);
    SBAR();
  }

  // ================= fused attention epilogue =================
  VMC(0);            // drain tail restages before LDS reuse
  __syncthreads();

  ushort* qls = (ushort*)smem;                     // [128][72]   36,864 B
  ushort* kls = (ushort*)(smem + 36864);           // [144][136]  39,168 B
  ushort* vls = (ushort*)(smem + 76032);           // V^T [64][152] 19,456 B
  ushort* Ps = (ushort*)(smem + 95488);            // [8][16][40] 10,240 B

  const int cc = lane & 15;
  const int cr4 = (lane >> 4) * 4;
  const int tmod = m0 & (SEQ_T - 1);

#pragma unroll 1
  for (int hf = 0; hf < 2; ++hf) {
    const int R0 = hf * 128;

    // ---- write phase: acc -> LDS (rows in this half's span)
#pragma unroll
    for (int mi = 0; mi < 4; ++mi) {
      const int lr = wr * 64 + mi * 16 + cr4;
#pragma unroll
      for (int j = 0; j < 6; ++j) {
        const int cb = wc * 96 + j * 16;
#pragma unroll
        for (int r = 0; r < 4; ++r) {
          const int row = lr + r;
          const ushort hv = f2bf(acc[mi][j][r]);
          if (cb < 64) {                       // q
            if (row >= R0 && row < R0 + 128) qls[(row - R0) * 72 + cb + cc] = hv;
          } else if (cb < 128) {               // k
            const int rr = row - R0 + 16;
            if (rr >= 0 && rr < 144) kls[rr * 136 + (cb - 64) + cc] = hv;
          } else {                             // v (transposed)
            const int rr = row - R0 + 16;
            if (rr >= 0 && rr < 144) vls[((cb - 128) + cc) * 152 + rr] = hv;
          }
        }
      }
    }
    if (hf == 0 && tid < 256) {  // boundary rows 0..15 from bkv (masked if batch start)
      const int r = tid >> 4;
      const int c8 = (tid & 15) * 8;
      u16x8 u = *(const u16x8*)(bkv + (size_t)(blockIdx.y * 16 + r) * 2048 + h * 128 + c8);
      if (c8 < 64) {
        *(u16x8*)&kls[r * 136 + c8] = u;
      } else {
#pragma unroll
        for (int jj = 0; jj < 8; ++jj) vls[(c8 - 64 + jj) * 152 + r] = u[jj];
      }
    }
    __syncthreads();

    // ---- compute phase: wave wid owns local t rows [R0 + wid*16, +15]
    bf16x8 qa[2];
#pragma unroll
    for (int kk = 0; kk < 2; ++kk)
      qa[kk] = *(const bf16x8*)&qls[(wid * 16 + fr) * 72 + kk * 32 + g * 8];

    f32x4 sacc[2];
    sacc[0] = (f32x4){0.f, 0.f, 0.f, 0.f};
    sacc[1] = (f32x4){0.f, 0.f, 0.f, 0.f};
#pragma unroll
    for (int kk = 0; kk < 2; ++kk)
#pragma unroll
      for (int nt = 0; nt < 2; ++nt) {
        bf16x8 kb = *(const bf16x8*)&kls[(wid * 16 + nt * 16 + fr) * 136 + kk * 32 + g * 8];
        sacc[nt] = __builtin_amdgcn_mfma_f32_16x16x32_bf16(qa[kk], kb, sacc[nt], 0, 0, 0);
      }

    const int tb = tmod + R0 + wid * 16;  // batch-time of this wave's first q row
#pragma unroll
    for (int nt = 0; nt < 2; ++nt) {
      const int kvr = nt * 16 + fr - 16;  // key time rel. to wave's first q row
#pragma unroll
      for (int reg = 0; reg < 4; ++reg) {
        const int qr = g * 4 + reg;
        float tau = 0.f;
        if (kvr >= qr - WIN && kvr <= qr - 1 && tb + kvr >= 0)
          tau = 1.f / (1.f + __expf(-sacc[nt][reg] * 0.125f));
        Ps[wid * 640 + (g * 4 + reg) * 40 + nt * 16 + fr] = f2bf(tau);
      }
    }
    __syncthreads();

    bf16x8 pa = *(const bf16x8*)&Ps[wid * 640 + fr * 40 + g * 8];
#pragma unroll
    for (int ct = 0; ct < 4; ++ct) {
      bf16x8 vb = *(const bf16x8*)&vls[(ct * 16 + fr) * 152 + wid * 16 + g * 8];
      f32x4 mres = __builtin_amdgcn_mfma_f32_16x16x32_bf16(pa, vb, (f32x4){0.f, 0.f, 0.f, 0.f},
                                                           0, 0, 0);
#pragma unroll
      for (int reg = 0; reg < 4; ++reg) {
        const int row = m0 + R0 + wid * 16 + g * 4 + reg;
        msg[(size_t)row * 1024 + h * 64 + ct * 16 + fr] = f2bf(mres[reg]);
      }
    }
    __syncthreads();
  }
#undef SA
#undef SB
#undef RD_A
#undef RD_B
#undef MM
}

// ---------------------------------------------------------------- GEMM2: 256x128, 8 waves 4Mx2N
template <int EPI>
__global__ __launch_bounds__(512, 2) void gemm_8w(const ushort* __restrict__ A,
                                                  const ushort* __restrict__ Bt,
                                                  ushort* __restrict__ Cb,
                                                  float* __restrict__ Cf,
                                                  const float* __restrict__ resid,
                                                  int M, int N, int K) {
  extern __shared__ char smem[];  // 98304 bytes
  const int NTK = K >> 6;
  const int tid = threadIdx.x;
  const int wid = tid >> 6;
  const int lane = tid & 63;
  const int m0 = blockIdx.y * 256;
  const int n0 = blockIdx.x * 128;

  const int l8 = lane >> 3;
  const int lchunk = (lane & 7) ^ (l8 & 7);
  const ushort* pA = A + (size_t)(m0 + wid * 8 + l8) * K + lchunk * 8;
  const ushort* pB = Bt + (size_t)(n0 + wid * 8 + l8) * K + lchunk * 8;

#define STAGE_A(kt, db)                                                                    \
  {                                                                                        \
    _Pragma("unroll") for (int j = 0; j < 4; ++j) {                                        \
      const ushort* gp = pA + (size_t)(j * 64) * K + (size_t)(kt) * 64;                    \
      char* lp = smem + (db) * 32768 + (j * 8 + wid) * 1024;                               \
      __builtin_amdgcn_global_load_lds((const __attribute__((address_space(1))) void*)gp,  \
                                       (__attribute__((address_space(3))) void*)lp, 16, 0, 0); \
    }                                                                                      \
  }
#define STAGE_B(kt, db)                                                                    \
  {                                                                                        \
    _Pragma("unroll") for (int j = 0; j < 2; ++j) {                                        \
      const ushort* gp = pB + (size_t)(j * 64) * K + (size_t)(kt) * 64;                    \
      char* lp = smem + 65536 + (db) * 16384 + (j * 8 + wid) * 1024;                       \
      __builtin_amdgcn_global_load_lds((const __attribute__((address_space(1))) void*)gp,  \
                                       (__attribute__((address_space(3))) void*)lp, 16, 0, 0); \
    }                                                                                      \
  }

  const int fr = lane & 15;
  const int g = lane >> 4;
  const int wr = wid >> 1;
  const int wc = wid & 1;
  int aRow[4], bRow[2][2], ch[2];
#pragma unroll
  for (int mi = 0; mi < 4; ++mi) aRow[mi] = (wr * 64 + mi * 16 + fr) * 128;
#pragma unroll
  for (int nq = 0; nq < 2; ++nq)
#pragma unroll
    for (int ni = 0; ni < 2; ++ni) bRow[nq][ni] = (wc * 64 + nq * 32 + ni * 16 + fr) * 128;
#pragma unroll
  for (int kk = 0; kk < 2; ++kk) ch[kk] = ((kk * 4 + g) ^ (fr & 7)) * 16;

  f32x4 acc[2][4][2];
#pragma unroll
  for (int nq = 0; nq < 2; ++nq)
#pragma unroll
    for (int mi = 0; mi < 4; ++mi)
#pragma unroll
      for (int ni = 0; ni < 2; ++ni) acc[nq][mi][ni] = (f32x4){0.f, 0.f, 0.f, 0.f};

  bf16x8 a[4][2], b0[2][2], b1[2][2];

  STAGE_A(0, 0); STAGE_B(0, 0); STAGE_A(1, 1);
  VMC(4);
  SBAR();

#define PHASE_MFMA(nq, bfr)                                                    \
  __builtin_amdgcn_s_setprio(1);                                               \
  _Pragma("unroll") for (int kk = 0; kk < 2; ++kk)                             \
    _Pragma("unroll") for (int mi = 0; mi < 4; ++mi)                           \
      _Pragma("unroll") for (int ni = 0; ni < 2; ++ni)                         \
        acc[nq][mi][ni] = __builtin_amdgcn_mfma_f32_16x16x32_bf16(             \
            a[mi][kk], bfr[ni][kk], acc[nq][mi][ni], 0, 0, 0);                 \
  __builtin_amdgcn_s_setprio(0);

#pragma unroll 1
  for (int t = 0; t < NTK; ++t) {
    const int db = t & 1;
    const int u1 = (t + 1 < NTK) ? t + 1 : NTK - 1;
    const int u2 = (t + 2 < NTK) ? t + 2 : NTK - 1;
    const int d1 = u1 & 1, d2 = u2 & 1;
    const char* Ab = smem + db * 32768;
    const char* Bb = smem + 65536 + db * 16384;

#pragma unroll
    for (int mi = 0; mi < 4; ++mi)
#pragma unroll
      for (int kk = 0; kk < 2; ++kk)
        a[mi][kk] = *(const bf16x8*)(Ab + aRow[mi] + ch[kk]);
#pragma unroll
    for (int ni = 0; ni < 2; ++ni)
#pragma unroll
      for (int kk = 0; kk < 2; ++kk)
        b0[ni][kk] = *(const bf16x8*)(Bb + bRow[0][ni] + ch[kk]);
    STAGE_B(u1, d1);
    LGKM0();
    PHASE_MFMA(0, b0);
    VMC(2);
    SBAR();

#pragma unroll
    for (int ni = 0; ni < 2; ++ni)
#pragma unroll
      for (int kk = 0; kk < 2; ++kk)
        b1[ni][kk] = *(const bf16x8*)(Bb + bRow[1][ni] + ch[kk]);
    STAGE_A(u2, d2);
    LGKM0();
    PHASE_MFMA(1, b1);
    VMC(4);
    SBAR();
  }

  const int cc = lane & 15;
  const int cr4 = (lane >> 4) * 4;
#pragma unroll
  for (int nq = 0; nq < 2; ++nq)
#pragma unroll
    for (int mi = 0; mi < 4; ++mi)
#pragma unroll
      for (int ni = 0; ni < 2; ++ni)
#pragma unroll
        for (int r = 0; r < 4; ++r) {
          int row = m0 + wr * 64 + mi * 16 + cr4 + r;
          int col = n0 + wc * 64 + nq * 32 + ni * 16 + cc;
          size_t idx = (size_t)row * N + col;
          float v = acc[nq][mi][ni][r];
          if (EPI == 0) {
            Cb[idx] = f2bf(v);
          } else {
            Cf[idx] = v + resid[idx];
          }
        }
#undef STAGE_A
#undef STAGE_B
#undef PHASE_MFMA
}

// ---------------------------------------------------------------- in-place LayerNorm (row=1024)
__global__ __launch_bounds__(256) void layernorm_inplace(float* __restrict__ y,
                                                         const float* __restrict__ gamma,
                                                         const float* __restrict__ beta) {
  const int row = blockIdx.x;
  float* p = y + (size_t)row * D_MODEL;
  const int tid = threadIdx.x;
  float4 v = *(const float4*)&p[tid * 4];
  float s = v.x + v.y + v.z + v.w;
  float s2 = v.x * v.x + v.y * v.y + v.z * v.z + v.w * v.w;
#pragma unroll
  for (int m = 1; m < 64; m <<= 1) {
    s += __shfl_xor(s, m);
    s2 += __shfl_xor(s2, m);
  }
  __shared__ float red[8];
  const int wave = tid >> 6, lane = tid & 63;
  if (lane == 0) { red[wave] = s; red[4 + wave] = s2; }
  __syncthreads();
  s = red[0] + red[1] + red[2] + red[3];
  s2 = red[4] + red[5] + red[6] + red[7];
  const float mu = s * (1.f / D_MODEL);
  const float var = s2 * (1.f / D_MODEL) - mu * mu;
  const float rstd = rsqrtf(var + 1e-5f);
  float4 g = *(const float4*)&gamma[tid * 4];
  float4 be = *(const float4*)&beta[tid * 4];
  float4 o;
  o.x = (v.x - mu) * rstd * g.x + be.x;
  o.y = (v.y - mu) * rstd * g.y + be.y;
  o.z = (v.z - mu) * rstd * g.z + be.z;
  o.w = (v.w - mu) * rstd * g.w + be.w;
  *(float4*)&p[tid * 4] = o;
}

// ---------------------------------------------------------------- launch
extern "C" void kernel_launch(void* const* d_in, const int* in_sizes, int n_in,
                              void* d_out, int out_size, void* d_ws, size_t ws_size,
                              hipStream_t stream) {
  (void)in_sizes; (void)n_in; (void)out_size; (void)ws_size;
  const float* x = (const float*)d_in[0];
  const float* wq = (const float*)d_in[1];
  const float* wkv = (const float*)d_in[2];
  const float* wo = (const float*)d_in[3];
  const float* gamma = (const float*)d_in[4];
  const float* beta = (const float*)d_in[5];
  float* out = (float*)d_out;

  ushort* xb = (ushort*)d_ws;                          // 8192x1024
  ushort* wb = xb + (size_t)8192 * 1024;               // 4096x1024 head-major [qkv]x16 + wo
  ushort* msgb = wb + (size_t)4096 * 1024;             // 8192x1024
  ushort* bkv = msgb + (size_t)8192 * 1024;            // 512x2048 boundary k/v

  const int M = NBATCH * SEQ_T;  // 8192

  (void)hipFuncSetAttribute(reinterpret_cast<const void*>(&gemm1_fused),
                            hipFuncAttributeMaxDynamicSharedMemorySize, 114688);
  (void)hipFuncSetAttribute(reinterpret_cast<const void*>(&gemm_8w<1>),
                            hipFuncAttributeMaxDynamicSharedMemorySize, 98304);

  cast_f32_bf16<<<(M * D_MODEL / 4 + 255) / 256, 256, 0, stream>>>((const float4*)x, xb,
                                                                   M * D_MODEL / 4);
  cast_weights<<<4096, 256, 0, stream>>>((const float4*)wq, (const float4*)wkv,
                                         (const float4*)wo, wb);

  // boundary k/v rows for each 256-row m-block (2.1 GF)
  pre_kv<<<dim3(M / 256, NHEADS), 256, 0, stream>>>(xb, wb, bkv);

  // fused: qkv projection (head-major) + sliding-window attention -> msg
  gemm1_fused<<<dim3(NHEADS, M / 256), 512, 114688, stream>>>(xb, wb, bkv, msgb, M, 1024);

  // GEMM2: y = x + msg @ wo^T  -> d_out (fp32)
  gemm_8w<1><<<dim3(1024 / 128, M / 256), 512, 98304, stream>>>(msgb, wb + (size_t)3072 * 1024,
                                                                nullptr, out, x, M, 1024, 1024);

  // LayerNorm in place on d_out
  layernorm_inplace<<<M, 256, 0, stream>>>(out, gamma, beta);
}

// Round 9
// 137.364 us; speedup vs baseline: 1.1391x; 1.1391x over previous
//
#include <hip/hip_runtime.h>
#include <hip/hip_bf16.h>

// Problem constants (B=2, T=4096, D=1024, H=16, HD=64, W=16)
#define D_MODEL 1024
#define SEQ_T   4096
#define NBATCH  2
#define NHEADS  16
#define HEAD_D  64
#define WIN     16

typedef __attribute__((ext_vector_type(8))) short bf16x8;           // MFMA A/B frag
typedef __attribute__((ext_vector_type(8))) unsigned short u16x8;   // 16B bf16 load
typedef __attribute__((ext_vector_type(4))) float f32x4;            // MFMA C/D frag

__device__ __forceinline__ unsigned short f2bf(float f) {
  union { float f; unsigned int u; } v; v.f = f;
  unsigned int r = v.u + 0x7fffu + ((v.u >> 16) & 1u);  // RNE
  return (unsigned short)(r >> 16);
}
__device__ __forceinline__ float bf2f(unsigned short u) {
  union { unsigned int u; float f; } v; v.u = ((unsigned int)u) << 16;
  return v.f;
}

#define SBAR() __builtin_amdgcn_s_barrier()
#define LGKM0() asm volatile("s_waitcnt lgkmcnt(0)" ::: "memory")
#define LGKM8() asm volatile("s_waitcnt lgkmcnt(8)" ::: "memory")
#define VMC(n) asm volatile("s_waitcnt vmcnt(" #n ")" ::: "memory")

// ---------------------------------------------------------------- casts
__global__ __launch_bounds__(256) void cast_f32_bf16(const float4* __restrict__ src,
                                                     ushort* __restrict__ dst, int n4) {
  int i = blockIdx.x * 256 + threadIdx.x;
  if (i >= n4) return;
  float4 v = src[i];
  ushort4 o;
  o.x = f2bf(v.x); o.y = f2bf(v.y); o.z = f2bf(v.z); o.w = f2bf(v.w);
  *(ushort4*)(dst + (size_t)i * 4) = o;
}

// merged weight cast: dst = [wq 1M][wkv 2M][wo 1M] bf16; i indexes float4 units (1M total)
__global__ __launch_bounds__(256) void cast_weights(const float4* __restrict__ wq,
                                                    const float4* __restrict__ wkv,
                                                    const float4* __restrict__ wo,
                                                    ushort* __restrict__ dst) {
  int i = blockIdx.x * 256 + threadIdx.x;  // 0..1048575
  const float4* src;
  int off;
  if (i < 262144) { src = wq; off = 0; }
  else if (i < 786432) { src = wkv; off = 262144; }
  else { src = wo; off = 786432; }
  float4 v = src[i - off];
  ushort4 o;
  o.x = f2bf(v.x); o.y = f2bf(v.y); o.z = f2bf(v.z); o.w = f2bf(v.w);
  *(ushort4*)(dst + (size_t)i * 4) = o;
}

// ---------------------------------------------------------------- GEMM1: 256x256 8-phase (de-fenced R3)
// C[m,n] = sum_k A[m,k]*Bt[n,k]; bf16 out. Grid 12x32 = 384 blocks (1.5 rounds).
// 512 thr = 8 waves (2M x 4N); per-wave per-quadrant 64x32; quadrants (mq,nq).
// LDS 128KiB: A[db][half][128][64] @0, B likewise @64KiB. Chunk-XOR swizzle both-sides.
// Phases/K-tile (m201 pattern, reads 12/4/8/0):
//   P0 (0,0): read A-h0(8)+B-h0(4); stage A1(t+1); lgkm8; SBAR; lgkm0; 16 MFMA; SBAR
//   P1 (0,1): read B-h1(4);         stage A0(t+2);        SBAR; lgkm0; 16 MFMA; SBAR
//   P2 (1,0): read A-h1(8);         stage B0(t+2);        SBAR; lgkm0; 16 MFMA; SBAR
//   P3 (1,1): no reads;             stage B1(t+2); vmcnt(6); SBAR; lgkm0; 16 MFMA; SBAR
// FIFO: before P3's vmcnt, 14 in flight; retire 8 -> tile t+1 complete; 6 remain (= prologue).
// Region safety: each stage's dest was last read >=1 exit-barrier earlier (R3-verified).
// NO sched_barrier anywhere (m141: fences cost 1.7x; this is the only change vs R3).
__global__ __launch_bounds__(512, 2) void gemm1_8ph(const ushort* __restrict__ A,
                                                    const ushort* __restrict__ Bt,
                                                    ushort* __restrict__ C,
                                                    int M, int N, int K) {
  extern __shared__ char smem[];  // 131072 bytes
  const int NTK = K >> 6;
  const int tid = threadIdx.x;
  const int wid = tid >> 6;
  const int lane = tid & 63;
  const int m0 = blockIdx.y * 256;
  const int n0 = blockIdx.x * 256;

  // staging lane geometry (pre-swizzled source chunk; involution c ^= row&7)
  const int l8 = lane >> 3;
  const int lchunk = (lane & 7) ^ (l8 & 7);
  const ushort* pA = A + (size_t)(m0 + wid * 16 + l8) * K + lchunk * 8;
  const ushort* pB = Bt + (size_t)(n0 + wid * 16 + l8) * K + lchunk * 8;

#define STAGE_A(h, kt, db)                                                                 \
  {                                                                                        \
    _Pragma("unroll") for (int j = 0; j < 2; ++j) {                                        \
      const ushort* gp = pA + (size_t)((h) * 128 + j * 8) * K + (size_t)(kt) * 64;         \
      char* lp = smem + (db) * 32768 + (h) * 16384 + (wid * 2 + j) * 1024;                 \
      __builtin_amdgcn_global_load_lds((const __attribute__((address_space(1))) void*)gp,  \
                                       (__attribute__((address_space(3))) void*)lp, 16, 0, 0); \
    }                                                                                      \
  }
#define STAGE_B(h, kt, db)                                                                 \
  {                                                                                        \
    _Pragma("unroll") for (int j = 0; j < 2; ++j) {                                        \
      const ushort* gp = pB + (size_t)((h) * 128 + j * 8) * K + (size_t)(kt) * 64;         \
      char* lp = smem + 65536 + (db) * 32768 + (h) * 16384 + (wid * 2 + j) * 1024;         \
      __builtin_amdgcn_global_load_lds((const __attribute__((address_space(1))) void*)gp,  \
                                       (__attribute__((address_space(3))) void*)lp, 16, 0, 0); \
    }                                                                                      \
  }

  // compute-side lane geometry
  const int fr = lane & 15;
  const int g = lane >> 4;
  const int wr = wid >> 2;   // 0..1
  const int wc = wid & 3;    // 0..3
  int aRow[4], bRow[2], ch[2];
#pragma unroll
  for (int mi = 0; mi < 4; ++mi) aRow[mi] = (wr * 64 + mi * 16 + fr) * 128;
#pragma unroll
  for (int ni = 0; ni < 2; ++ni) bRow[ni] = (wc * 32 + ni * 16 + fr) * 128;
#pragma unroll
  for (int kk = 0; kk < 2; ++kk) ch[kk] = ((kk * 4 + g) ^ (fr & 7)) * 16;

  f32x4 acc[2][2][4][2];
#pragma unroll
  for (int mq = 0; mq < 2; ++mq)
#pragma unroll
    for (int nq = 0; nq < 2; ++nq)
#pragma unroll
      for (int mi = 0; mi < 4; ++mi)
#pragma unroll
        for (int ni = 0; ni < 2; ++ni) acc[mq][nq][mi][ni] = (f32x4){0.f, 0.f, 0.f, 0.f};

  bf16x8 a[4][2], bf[2][2][2];

  // ---- prologue: tile0 {A0,B0,B1,A1} + tile1 {A0,B0,B1} = 14 loads; vmcnt(6) -> tile0 done
  STAGE_A(0, 0, 0); STAGE_B(0, 0, 0); STAGE_B(1, 0, 0); STAGE_A(1, 0, 0);
  STAGE_A(0, 1, 1); STAGE_B(0, 1, 1); STAGE_B(1, 1, 1);
  VMC(6);
  SBAR();

#define PHASE_MFMA(mq, nq)                                                     \
  __builtin_amdgcn_s_setprio(1);                                               \
  _Pragma("unroll") for (int kk = 0; kk < 2; ++kk)                             \
    _Pragma("unroll") for (int mi = 0; mi < 4; ++mi)                           \
      _Pragma("unroll") for (int ni = 0; ni < 2; ++ni)                         \
        acc[mq][nq][mi][ni] = __builtin_amdgcn_mfma_f32_16x16x32_bf16(         \
            a[mi][kk], bf[nq][ni][kk], acc[mq][nq][mi][ni], 0, 0, 0);          \
  __builtin_amdgcn_s_setprio(0);

#pragma unroll 1
  for (int t = 0; t < NTK; ++t) {
    const int db = t & 1;
    const int u1 = (t + 1 < NTK) ? t + 1 : NTK - 1;
    const int u2 = (t + 2 < NTK) ? t + 2 : NTK - 1;
    const int d1 = u1 & 1, d2 = u2 & 1;
    const char* Ab = smem + db * 32768;
    const char* Bb = smem + 65536 + db * 32768;

    // ---- P0 (0,0): read A-h0 (8) + B-h0 (4); stage A1(t+1)
#pragma unroll
    for (int mi = 0; mi < 4; ++mi)
#pragma unroll
      for (int kk = 0; kk < 2; ++kk)
        a[mi][kk] = *(const bf16x8*)(Ab + 0 * 16384 + aRow[mi] + ch[kk]);
#pragma unroll
    for (int ni = 0; ni < 2; ++ni)
#pragma unroll
      for (int kk = 0; kk < 2; ++kk)
        bf[0][ni][kk] = *(const bf16x8*)(Bb + 0 * 16384 + bRow[ni] + ch[kk]);
    STAGE_A(1, u1, d1);
    LGKM8();
    SBAR(); LGKM0();
    PHASE_MFMA(0, 0);
    SBAR();

    // ---- P1 (0,1): read B-h1 (4); stage A0(t+2)  [A0 region read-complete at P0 entry]
#pragma unroll
    for (int ni = 0; ni < 2; ++ni)
#pragma unroll
      for (int kk = 0; kk < 2; ++kk)
        bf[1][ni][kk] = *(const bf16x8*)(Bb + 1 * 16384 + bRow[ni] + ch[kk]);
    STAGE_A(0, u2, d2);
    SBAR(); LGKM0();
    PHASE_MFMA(0, 1);
    SBAR();

    // ---- P2 (1,0): read A-h1 (8); stage B0(t+2)
#pragma unroll
    for (int mi = 0; mi < 4; ++mi)
#pragma unroll
      for (int kk = 0; kk < 2; ++kk)
        a[mi][kk] = *(const bf16x8*)(Ab + 1 * 16384 + aRow[mi] + ch[kk]);
    STAGE_B(0, u2, d2);
    SBAR(); LGKM0();
    PHASE_MFMA(1, 0);
    SBAR();

    // ---- P3 (1,1): no reads; stage B1(t+2); counted vmcnt(6)
    STAGE_B(1, u2, d2);
    VMC(6);
    SBAR(); LGKM0();
    PHASE_MFMA(1, 1);
    SBAR();
  }

  // ---- epilogue: C/D layout col=lane&15, row=(lane>>4)*4+r
  const int cc = lane & 15;
  const int cr4 = (lane >> 4) * 4;
#pragma unroll
  for (int mq = 0; mq < 2; ++mq)
#pragma unroll
    for (int nq = 0; nq < 2; ++nq)
#pragma unroll
      for (int mi = 0; mi < 4; ++mi)
#pragma unroll
        for (int ni = 0; ni < 2; ++ni)
#pragma unroll
          for (int r = 0; r < 4; ++r) {
            int row = m0 + mq * 128 + wr * 64 + mi * 16 + cr4 + r;
            int col = n0 + nq * 128 + wc * 32 + ni * 16 + cc;
            C[(size_t)row * N + col] = f2bf(acc[mq][nq][mi][ni][r]);
          }
#undef STAGE_A
#undef STAGE_B
#undef PHASE_MFMA
}

// ---------------------------------------------------------------- GEMM2: 256x128, 8 waves 4Mx2N
// (R5/R7 structure; 256 blocks = 1 round.) EPI=1: fp32 store + residual add.
template <int EPI>
__global__ __launch_bounds__(512, 2) void gemm_8w(const ushort* __restrict__ A,
                                                  const ushort* __restrict__ Bt,
                                                  ushort* __restrict__ Cb,
                                                  float* __restrict__ Cf,
                                                  const float* __restrict__ resid,
                                                  int M, int N, int K) {
  extern __shared__ char smem[];  // 98304 bytes
  const int NTK = K >> 6;
  const int tid = threadIdx.x;
  const int wid = tid >> 6;
  const int lane = tid & 63;
  const int m0 = blockIdx.y * 256;
  const int n0 = blockIdx.x * 128;

  const int l8 = lane >> 3;
  const int lchunk = (lane & 7) ^ (l8 & 7);
  const ushort* pA = A + (size_t)(m0 + wid * 8 + l8) * K + lchunk * 8;
  const ushort* pB = Bt + (size_t)(n0 + wid * 8 + l8) * K + lchunk * 8;

#define STAGE_A(kt, db)                                                                    \
  {                                                                                        \
    _Pragma("unroll") for (int j = 0; j < 4; ++j) {                                        \
      const ushort* gp = pA + (size_t)(j * 64) * K + (size_t)(kt) * 64;                    \
      char* lp = smem + (db) * 32768 + (j * 8 + wid) * 1024;                               \
      __builtin_amdgcn_global_load_lds((const __attribute__((address_space(1))) void*)gp,  \
                                       (__attribute__((address_space(3))) void*)lp, 16, 0, 0); \
    }                                                                                      \
  }
#define STAGE_B(kt, db)                                                                    \
  {                                                                                        \
    _Pragma("unroll") for (int j = 0; j < 2; ++j) {                                        \
      const ushort* gp = pB + (size_t)(j * 64) * K + (size_t)(kt) * 64;                    \
      char* lp = smem + 65536 + (db) * 16384 + (j * 8 + wid) * 1024;                       \
      __builtin_amdgcn_global_load_lds((const __attribute__((address_space(1))) void*)gp,  \
                                       (__attribute__((address_space(3))) void*)lp, 16, 0, 0); \
    }                                                                                      \
  }

  const int fr = lane & 15;
  const int g = lane >> 4;
  const int wr = wid >> 1;
  const int wc = wid & 1;
  int aRow[4], bRow[2][2], ch[2];
#pragma unroll
  for (int mi = 0; mi < 4; ++mi) aRow[mi] = (wr * 64 + mi * 16 + fr) * 128;
#pragma unroll
  for (int nq = 0; nq < 2; ++nq)
#pragma unroll
    for (int ni = 0; ni < 2; ++ni) bRow[nq][ni] = (wc * 64 + nq * 32 + ni * 16 + fr) * 128;
#pragma unroll
  for (int kk = 0; kk < 2; ++kk) ch[kk] = ((kk * 4 + g) ^ (fr & 7)) * 16;

  f32x4 acc[2][4][2];
#pragma unroll
  for (int nq = 0; nq < 2; ++nq)
#pragma unroll
    for (int mi = 0; mi < 4; ++mi)
#pragma unroll
      for (int ni = 0; ni < 2; ++ni) acc[nq][mi][ni] = (f32x4){0.f, 0.f, 0.f, 0.f};

  bf16x8 a[4][2], b0[2][2], b1[2][2];

  STAGE_A(0, 0); STAGE_B(0, 0); STAGE_A(1, 1);
  VMC(4);
  SBAR();

#define PHASE_MFMA(nq, bfr)                                                    \
  __builtin_amdgcn_s_setprio(1);                                               \
  _Pragma("unroll") for (int kk = 0; kk < 2; ++kk)                             \
    _Pragma("unroll") for (int mi = 0; mi < 4; ++mi)                           \
      _Pragma("unroll") for (int ni = 0; ni < 2; ++ni)                         \
        acc[nq][mi][ni] = __builtin_amdgcn_mfma_f32_16x16x32_bf16(             \
            a[mi][kk], bfr[ni][kk], acc[nq][mi][ni], 0, 0, 0);                 \
  __builtin_amdgcn_s_setprio(0);

#pragma unroll 1
  for (int t = 0; t < NTK; ++t) {
    const int db = t & 1;
    const int u1 = (t + 1 < NTK) ? t + 1 : NTK - 1;
    const int u2 = (t + 2 < NTK) ? t + 2 : NTK - 1;
    const int d1 = u1 & 1, d2 = u2 & 1;
    const char* Ab = smem + db * 32768;
    const char* Bb = smem + 65536 + db * 16384;

#pragma unroll
    for (int mi = 0; mi < 4; ++mi)
#pragma unroll
      for (int kk = 0; kk < 2; ++kk)
        a[mi][kk] = *(const bf16x8*)(Ab + aRow[mi] + ch[kk]);
#pragma unroll
    for (int ni = 0; ni < 2; ++ni)
#pragma unroll
      for (int kk = 0; kk < 2; ++kk)
        b0[ni][kk] = *(const bf16x8*)(Bb + bRow[0][ni] + ch[kk]);
    STAGE_B(u1, d1);
    LGKM0();
    PHASE_MFMA(0, b0);
    VMC(2);
    SBAR();

#pragma unroll
    for (int ni = 0; ni < 2; ++ni)
#pragma unroll
      for (int kk = 0; kk < 2; ++kk)
        b1[ni][kk] = *(const bf16x8*)(Bb + bRow[1][ni] + ch[kk]);
    STAGE_A(u2, d2);
    LGKM0();
    PHASE_MFMA(1, b1);
    VMC(4);
    SBAR();
  }

  const int cc = lane & 15;
  const int cr4 = (lane >> 4) * 4;
#pragma unroll
  for (int nq = 0; nq < 2; ++nq)
#pragma unroll
    for (int mi = 0; mi < 4; ++mi)
#pragma unroll
      for (int ni = 0; ni < 2; ++ni)
#pragma unroll
        for (int r = 0; r < 4; ++r) {
          int row = m0 + wr * 64 + mi * 16 + cr4 + r;
          int col = n0 + wc * 64 + nq * 32 + ni * 16 + cc;
          size_t idx = (size_t)row * N + col;
          float v = acc[nq][mi][ni][r];
          if (EPI == 0) {
            Cb[idx] = f2bf(v);
          } else {
            Cf[idx] = v + resid[idx];
          }
        }
#undef STAGE_A
#undef STAGE_B
#undef PHASE_MFMA
}

// ---------------------------------------------------------------- sliding-window attention (MFMA band)
__global__ __launch_bounds__(256) void attn_win_mfma(const ushort* __restrict__ qkv,
                                                     ushort* __restrict__ msg) {
  __shared__ ushort Ks[80][72];
  __shared__ ushort Vt[64][88];
  __shared__ ushort Ps[4][16][40];

  const int tile = blockIdx.x;
  const int h = blockIdx.y;
  const int b = blockIdx.z;
  const int t0 = tile * 64;
  const size_t rowbase = (size_t)b * SEQ_T;
  const int tid = threadIdx.x;
  const int wave = tid >> 6;
  const int lane = tid & 63;

  for (int chunk = tid; chunk < 1280; chunk += 256) {
    int r = chunk >> 4;
    int c = (chunk & 15) * 8;
    int t = t0 - 16 + r;
    u16x8 u = {0, 0, 0, 0, 0, 0, 0, 0};
    if (t >= 0)
      u = *(const u16x8*)(qkv + (rowbase + t) * 3072 + 1024 + (size_t)h * 128 + c);
    if (c < 64) {
      *(u16x8*)&Ks[r][c] = u;
    } else {
      int d0 = c - 64;
#pragma unroll
      for (int j = 0; j < 8; ++j) Vt[d0 + j][r] = u[j];
    }
  }
  __syncthreads();

  const int fr = lane & 15;
  const int g = lane >> 4;
  const int rbase = wave * 16;

  bf16x8 qa[2];
#pragma unroll
  for (int kk = 0; kk < 2; ++kk)
    qa[kk] = *(const bf16x8*)(qkv + (rowbase + t0 + wave * 16 + fr) * 3072 +
                              (size_t)h * 64 + kk * 32 + g * 8);

  f32x4 sacc[2];
  sacc[0] = (f32x4){0.f, 0.f, 0.f, 0.f};
  sacc[1] = (f32x4){0.f, 0.f, 0.f, 0.f};
#pragma unroll
  for (int kk = 0; kk < 2; ++kk) {
#pragma unroll
    for (int nt = 0; nt < 2; ++nt) {
      bf16x8 kb = *(const bf16x8*)&Ks[rbase + nt * 16 + fr][kk * 32 + g * 8];
      sacc[nt] = __builtin_amdgcn_mfma_f32_16x16x32_bf16(qa[kk], kb, sacc[nt], 0, 0, 0);
    }
  }

#pragma unroll
  for (int nt = 0; nt < 2; ++nt) {
    int tk = t0 - 16 + rbase + nt * 16 + fr;
#pragma unroll
    for (int reg = 0; reg < 4; ++reg) {
      int t = t0 + wave * 16 + g * 4 + reg;
      float tau = 0.f;
      if (tk >= 0 && tk >= t - WIN && tk <= t - 1)
        tau = 1.f / (1.f + __expf(-sacc[nt][reg] * 0.125f));
      Ps[wave][g * 4 + reg][nt * 16 + fr] = f2bf(tau);
    }
  }
  __syncthreads();

  bf16x8 pa = *(const bf16x8*)&Ps[wave][fr][g * 8];
#pragma unroll
  for (int ct = 0; ct < 4; ++ct) {
    bf16x8 vb = *(const bf16x8*)&Vt[ct * 16 + fr][rbase + g * 8];
    f32x4 m = __builtin_amdgcn_mfma_f32_16x16x32_bf16(pa, vb, (f32x4){0.f, 0.f, 0.f, 0.f}, 0, 0, 0);
#pragma unroll
    for (int reg = 0; reg < 4; ++reg) {
      int t = t0 + wave * 16 + g * 4 + reg;
      msg[(rowbase + t) * 1024 + (size_t)h * 64 + ct * 16 + fr] = f2bf(m[reg]);
    }
  }
}

// ---------------------------------------------------------------- in-place LayerNorm (row=1024)
__global__ __launch_bounds__(256) void layernorm_inplace(float* __restrict__ y,
                                                         const float* __restrict__ gamma,
                                                         const float* __restrict__ beta) {
  const int row = blockIdx.x;
  float* p = y + (size_t)row * D_MODEL;
  const int tid = threadIdx.x;
  float4 v = *(const float4*)&p[tid * 4];
  float s = v.x + v.y + v.z + v.w;
  float s2 = v.x * v.x + v.y * v.y + v.z * v.z + v.w * v.w;
#pragma unroll
  for (int m = 1; m < 64; m <<= 1) {
    s += __shfl_xor(s, m);
    s2 += __shfl_xor(s2, m);
  }
  __shared__ float red[8];
  const int wave = tid >> 6, lane = tid & 63;
  if (lane == 0) { red[wave] = s; red[4 + wave] = s2; }
  __syncthreads();
  s = red[0] + red[1] + red[2] + red[3];
  s2 = red[4] + red[5] + red[6] + red[7];
  const float mu = s * (1.f / D_MODEL);
  const float var = s2 * (1.f / D_MODEL) - mu * mu;
  const float rstd = rsqrtf(var + 1e-5f);
  float4 g = *(const float4*)&gamma[tid * 4];
  float4 be = *(const float4*)&beta[tid * 4];
  float4 o;
  o.x = (v.x - mu) * rstd * g.x + be.x;
  o.y = (v.y - mu) * rstd * g.y + be.y;
  o.z = (v.z - mu) * rstd * g.z + be.z;
  o.w = (v.w - mu) * rstd * g.w + be.w;
  *(float4*)&p[tid * 4] = o;
}

// ---------------------------------------------------------------- launch
extern "C" void kernel_launch(void* const* d_in, const int* in_sizes, int n_in,
                              void* d_out, int out_size, void* d_ws, size_t ws_size,
                              hipStream_t stream) {
  (void)in_sizes; (void)n_in; (void)out_size; (void)ws_size;
  const float* x = (const float*)d_in[0];
  const float* wq = (const float*)d_in[1];
  const float* wkv = (const float*)d_in[2];
  const float* wo = (const float*)d_in[3];
  const float* gamma = (const float*)d_in[4];
  const float* beta = (const float*)d_in[5];
  float* out = (float*)d_out;

  ushort* xb = (ushort*)d_ws;                          // 8192x1024
  ushort* wb = xb + (size_t)8192 * 1024;               // 4096x1024: [wq;wkv;wo]
  ushort* qkvb = wb + (size_t)4096 * 1024;             // 8192x3072
  ushort* msgb = qkvb + (size_t)8192 * 3072;           // 8192x1024

  const int M = NBATCH * SEQ_T;  // 8192

  (void)hipFuncSetAttribute(reinterpret_cast<const void*>(&gemm1_8ph),
                            hipFuncAttributeMaxDynamicSharedMemorySize, 131072);
  (void)hipFuncSetAttribute(reinterpret_cast<const void*>(&gemm_8w<1>),
                            hipFuncAttributeMaxDynamicSharedMemorySize, 98304);

  cast_f32_bf16<<<(M * D_MODEL / 4 + 255) / 256, 256, 0, stream>>>((const float4*)x, xb,
                                                                   M * D_MODEL / 4);
  cast_weights<<<4096, 256, 0, stream>>>((const float4*)wq, (const float4*)wkv,
                                         (const float4*)wo, wb);

  // GEMM1: qkv = x @ [wq;wkv]^T  (M=8192, N=3072, K=1024) -> 12x32 = 384 blocks (1.5 rounds)
  gemm1_8ph<<<dim3(3072 / 256, M / 256), 512, 131072, stream>>>(xb, wb, qkvb, M, 3072, 1024);

  // windowed sigmoid attention -> msg (bf16), MFMA band formulation
  attn_win_mfma<<<dim3(SEQ_T / 64, NHEADS, NBATCH), 256, 0, stream>>>(qkvb, msgb);

  // GEMM2: y = x + msg @ wo^T  (M=8192, N=1024, K=1024) -> 8x32 = 256 blocks = 1 round
  gemm_8w<1><<<dim3(1024 / 128, M / 256), 512, 98304, stream>>>(msgb, wb + (size_t)3072 * 1024,
                                                                nullptr, out, x, M, 1024, 1024);

  // LayerNorm in place on d_out
  layernorm_inplace<<<M, 256, 0, stream>>>(out, gamma, beta);
}

// Round 10
// 125.641 us; speedup vs baseline: 1.2453x; 1.0933x over previous
//
#include <hip/hip_runtime.h>
#include <hip/hip_bf16.h>

// Problem constants (B=2, T=4096, D=1024, H=16, HD=64, W=16)
#define D_MODEL 1024
#define SEQ_T   4096
#define NBATCH  2
#define NHEADS  16
#define HEAD_D  64
#define WIN     16

typedef __attribute__((ext_vector_type(8))) short bf16x8;           // MFMA A/B frag
typedef __attribute__((ext_vector_type(8))) unsigned short u16x8;   // 16B bf16 load
typedef __attribute__((ext_vector_type(4))) float f32x4;            // MFMA C/D frag

__device__ __forceinline__ unsigned short f2bf(float f) {
  union { float f; unsigned int u; } v; v.f = f;
  unsigned int r = v.u + 0x7fffu + ((v.u >> 16) & 1u);  // RNE
  return (unsigned short)(r >> 16);
}
__device__ __forceinline__ float bf2f(unsigned short u) {
  union { unsigned int u; float f; } v; v.u = ((unsigned int)u) << 16;
  return v.f;
}

#define SBAR() __builtin_amdgcn_s_barrier()
#define LGKM0() asm volatile("s_waitcnt lgkmcnt(0)" ::: "memory")
#define LGKM8() asm volatile("s_waitcnt lgkmcnt(8)" ::: "memory")
#define VMC(n) asm volatile("s_waitcnt vmcnt(" #n ")" ::: "memory")

// ---------------------------------------------------------------- merged cast kernel
// i < 2M: x -> xb. else: weights -> wb ([wq 1M][wkv 2M][wo 1M] rows).
__global__ __launch_bounds__(256) void cast_all(const float4* __restrict__ x,
                                                const float4* __restrict__ wq,
                                                const float4* __restrict__ wkv,
                                                const float4* __restrict__ wo,
                                                ushort* __restrict__ xb,
                                                ushort* __restrict__ wb) {
  int i = blockIdx.x * 256 + threadIdx.x;  // 0..3145727 float4 units
  float4 v;
  ushort* dst;
  if (i < 2097152) {
    v = x[i];
    dst = xb + (size_t)i * 4;
  } else {
    int j = i - 2097152;  // 0..1048575
    const float4* src;
    int off;
    if (j < 262144) { src = wq; off = 0; }
    else if (j < 786432) { src = wkv; off = 262144; }
    else { src = wo; off = 786432; }
    v = src[j - off];
    dst = wb + (size_t)j * 4;
  }
  ushort4 o;
  o.x = f2bf(v.x); o.y = f2bf(v.y); o.z = f2bf(v.z); o.w = f2bf(v.w);
  *(ushort4*)dst = o;
}

// ---------------------------------------------------------------- GEMM1: 256x192, 6-phase/2-K-tile
// (R7 winner — unchanged.) Grid 16x32 = 512 blocks = 2.0 rounds. 8 waves 4Mx2N.
// LDS 112KiB: A[2][256][64] @0, B[2][192][64] @64KiB. Chunk-XOR swizzle both-sides.
// One stage unit per phase, placed after its region's last reader; vmcnt(4) at p3/p6.
__global__ __launch_bounds__(512, 2) void gemm1_6ph(const ushort* __restrict__ A,
                                                    const ushort* __restrict__ Bt,
                                                    ushort* __restrict__ C,
                                                    int M, int N, int K) {
  extern __shared__ char smem[];  // 114688 bytes
  const int tid = threadIdx.x;
  const int wid = tid >> 6;
  const int lane = tid & 63;
  const int m0 = blockIdx.y * 256;
  const int n0 = blockIdx.x * 192;

  const int l8 = lane >> 3;
  const int lchunk = (lane & 7) ^ (l8 & 7);
  const ushort* pA = A + (size_t)(m0 + wid * 8 + l8) * K + lchunk * 8;
  const ushort* pB = Bt + (size_t)(n0 + wid * 8 + l8) * K + lchunk * 8;

#define SA(kt, db, j0)                                                                     \
  {                                                                                        \
    _Pragma("unroll") for (int j = (j0); j < (j0) + 2; ++j) {                              \
      const ushort* gp = pA + (size_t)(j * 64) * K + (size_t)(kt) * 64;                    \
      char* lp = smem + (db) * 32768 + (j * 8 + wid) * 1024;                               \
      __builtin_amdgcn_global_load_lds((const __attribute__((address_space(1))) void*)gp,  \
                                       (__attribute__((address_space(3))) void*)lp, 16, 0, 0); \
    }                                                                                      \
  }
#define SB(kt, db)                                                                         \
  {                                                                                        \
    _Pragma("unroll") for (int j = 0; j < 3; ++j) {                                        \
      const ushort* gp = pB + (size_t)(j * 64) * K + (size_t)(kt) * 64;                    \
      char* lp = smem + 65536 + (db) * 24576 + (j * 8 + wid) * 1024;                       \
      __builtin_amdgcn_global_load_lds((const __attribute__((address_space(1))) void*)gp,  \
                                       (__attribute__((address_space(3))) void*)lp, 16, 0, 0); \
    }                                                                                      \
  }

  const int fr = lane & 15;
  const int g = lane >> 4;
  const int wr = wid >> 1;   // 0..3
  const int wc = wid & 1;    // 0..1
  int aRow[4], bRow[6], ch[2];
#pragma unroll
  for (int mi = 0; mi < 4; ++mi) aRow[mi] = (wr * 64 + mi * 16 + fr) * 128;
#pragma unroll
  for (int j = 0; j < 6; ++j) bRow[j] = (wc * 96 + j * 16 + fr) * 128;
#pragma unroll
  for (int kk = 0; kk < 2; ++kk) ch[kk] = ((kk * 4 + g) ^ (fr & 7)) * 16;

  f32x4 acc[4][6];
#pragma unroll
  for (int mi = 0; mi < 4; ++mi)
#pragma unroll
    for (int j = 0; j < 6; ++j) acc[mi][j] = (f32x4){0.f, 0.f, 0.f, 0.f};

  bf16x8 a[4][2], b[2][2];

#define RD_A(db)                                                               \
  _Pragma("unroll") for (int mi = 0; mi < 4; ++mi)                             \
    _Pragma("unroll") for (int kk = 0; kk < 2; ++kk)                           \
      a[mi][kk] = *(const bf16x8*)(smem + (db) * 32768 + aRow[mi] + ch[kk]);
#define RD_B(db, nh)                                                           \
  _Pragma("unroll") for (int ni = 0; ni < 2; ++ni)                             \
    _Pragma("unroll") for (int kk = 0; kk < 2; ++kk)                           \
      b[ni][kk] = *(const bf16x8*)(smem + 65536 + (db) * 24576 +               \
                                   bRow[(nh) * 2 + ni] + ch[kk]);
#define MM(nh)                                                                 \
  __builtin_amdgcn_s_setprio(1);                                               \
  _Pragma("unroll") for (int kk = 0; kk < 2; ++kk)                             \
    _Pragma("unroll") for (int mi = 0; mi < 4; ++mi)                           \
      _Pragma("unroll") for (int ni = 0; ni < 2; ++ni)                         \
        acc[mi][(nh) * 2 + ni] = __builtin_amdgcn_mfma_f32_16x16x32_bf16(      \
            a[mi][kk], b[ni][kk], acc[mi][(nh) * 2 + ni], 0, 0, 0);            \
  __builtin_amdgcn_s_setprio(0);

  SA(0, 0, 0); SA(0, 0, 2); SB(0, 0); SA(1, 1, 0); SA(1, 1, 2);
  VMC(4);
  SBAR();

#pragma unroll 1
  for (int i = 0; i < 8; ++i) {
    const int t1 = 2 * i + 1;
    const int t2 = (2 * i + 2 < 16) ? 2 * i + 2 : 15;
    const int t3 = (2 * i + 3 < 16) ? 2 * i + 3 : 15;
    const int d2 = t2 & 1, d3 = t3 & 1;

    RD_A(0); RD_B(0, 0);
    SB(t1, 1);
    LGKM8();
    SBAR(); LGKM0();
    MM(0);
    SBAR();

    RD_B(0, 1);
    SA(t2, d2, 0);
    SBAR(); LGKM0();
    MM(1);
    SBAR();

    RD_B(0, 2);
    SA(t2, d2, 2);
    VMC(4);
    SBAR(); LGKM0();
    MM(2);
    SBAR();

    RD_A(1); RD_B(1, 0);
    SB(t2, d2);
    LGKM8();
    SBAR(); LGKM0();
    MM(0);
    SBAR();

    RD_B(1, 1);
    SA(t3, d3, 0);
    SBAR(); LGKM0();
    MM(1);
    SBAR();

    RD_B(1, 2);
    SA(t3, d3, 2);
    VMC(4);
    SBAR(); LGKM0();
    MM(2);
    SBAR();
  }

  const int cc = lane & 15;
  const int cr4 = (lane >> 4) * 4;
#pragma unroll
  for (int mi = 0; mi < 4; ++mi)
#pragma unroll
    for (int j = 0; j < 6; ++j)
#pragma unroll
      for (int r = 0; r < 4; ++r) {
        int row = m0 + wr * 64 + mi * 16 + cr4 + r;
        int col = n0 + wc * 96 + j * 16 + cc;
        C[(size_t)row * N + col] = f2bf(acc[mi][j][r]);
      }
#undef SA
#undef SB
#undef RD_A
#undef RD_B
#undef MM
}

// ---------------------------------------------------------------- GEMM2: 256x128, bf16 resid + bf16 y out
// R5/R7 schedule; 256 blocks = 1 round. Yb[idx] = bf16(acc + bf2f(residb[idx])).
__global__ __launch_bounds__(512, 2) void gemm2_b(const ushort* __restrict__ A,
                                                  const ushort* __restrict__ Bt,
                                                  const ushort* __restrict__ residb,
                                                  ushort* __restrict__ Yb,
                                                  int M, int N, int K) {
  extern __shared__ char smem[];  // 98304 bytes
  const int NTK = K >> 6;
  const int tid = threadIdx.x;
  const int wid = tid >> 6;
  const int lane = tid & 63;
  const int m0 = blockIdx.y * 256;
  const int n0 = blockIdx.x * 128;

  const int l8 = lane >> 3;
  const int lchunk = (lane & 7) ^ (l8 & 7);
  const ushort* pA = A + (size_t)(m0 + wid * 8 + l8) * K + lchunk * 8;
  const ushort* pB = Bt + (size_t)(n0 + wid * 8 + l8) * K + lchunk * 8;

#define STAGE_A(kt, db)                                                                    \
  {                                                                                        \
    _Pragma("unroll") for (int j = 0; j < 4; ++j) {                                        \
      const ushort* gp = pA + (size_t)(j * 64) * K + (size_t)(kt) * 64;                    \
      char* lp = smem + (db) * 32768 + (j * 8 + wid) * 1024;                               \
      __builtin_amdgcn_global_load_lds((const __attribute__((address_space(1))) void*)gp,  \
                                       (__attribute__((address_space(3))) void*)lp, 16, 0, 0); \
    }                                                                                      \
  }
#define STAGE_B(kt, db)                                                                    \
  {                                                                                        \
    _Pragma("unroll") for (int j = 0; j < 2; ++j) {                                        \
      const ushort* gp = pB + (size_t)(j * 64) * K + (size_t)(kt) * 64;                    \
      char* lp = smem + 65536 + (db) * 16384 + (j * 8 + wid) * 1024;                       \
      __builtin_amdgcn_global_load_lds((const __attribute__((address_space(1))) void*)gp,  \
                                       (__attribute__((address_space(3))) void*)lp, 16, 0, 0); \
    }                                                                                      \
  }

  const int fr = lane & 15;
  const int g = lane >> 4;
  const int wr = wid >> 1;
  const int wc = wid & 1;
  int aRow[4], bRow[2][2], ch[2];
#pragma unroll
  for (int mi = 0; mi < 4; ++mi) aRow[mi] = (wr * 64 + mi * 16 + fr) * 128;
#pragma unroll
  for (int nq = 0; nq < 2; ++nq)
#pragma unroll
    for (int ni = 0; ni < 2; ++ni) bRow[nq][ni] = (wc * 64 + nq * 32 + ni * 16 + fr) * 128;
#pragma unroll
  for (int kk = 0; kk < 2; ++kk) ch[kk] = ((kk * 4 + g) ^ (fr & 7)) * 16;

  f32x4 acc[2][4][2];
#pragma unroll
  for (int nq = 0; nq < 2; ++nq)
#pragma unroll
    for (int mi = 0; mi < 4; ++mi)
#pragma unroll
      for (int ni = 0; ni < 2; ++ni) acc[nq][mi][ni] = (f32x4){0.f, 0.f, 0.f, 0.f};

  bf16x8 a[4][2], b0[2][2], b1[2][2];

  STAGE_A(0, 0); STAGE_B(0, 0); STAGE_A(1, 1);
  VMC(4);
  SBAR();

#define PHASE_MFMA(nq, bfr)                                                    \
  __builtin_amdgcn_s_setprio(1);                                               \
  _Pragma("unroll") for (int kk = 0; kk < 2; ++kk)                             \
    _Pragma("unroll") for (int mi = 0; mi < 4; ++mi)                           \
      _Pragma("unroll") for (int ni = 0; ni < 2; ++ni)                         \
        acc[nq][mi][ni] = __builtin_amdgcn_mfma_f32_16x16x32_bf16(             \
            a[mi][kk], bfr[ni][kk], acc[nq][mi][ni], 0, 0, 0);                 \
  __builtin_amdgcn_s_setprio(0);

#pragma unroll 1
  for (int t = 0; t < NTK; ++t) {
    const int db = t & 1;
    const int u1 = (t + 1 < NTK) ? t + 1 : NTK - 1;
    const int u2 = (t + 2 < NTK) ? t + 2 : NTK - 1;
    const int d1 = u1 & 1, d2 = u2 & 1;
    const char* Ab = smem + db * 32768;
    const char* Bb = smem + 65536 + db * 16384;

#pragma unroll
    for (int mi = 0; mi < 4; ++mi)
#pragma unroll
      for (int kk = 0; kk < 2; ++kk)
        a[mi][kk] = *(const bf16x8*)(Ab + aRow[mi] + ch[kk]);
#pragma unroll
    for (int ni = 0; ni < 2; ++ni)
#pragma unroll
      for (int kk = 0; kk < 2; ++kk)
        b0[ni][kk] = *(const bf16x8*)(Bb + bRow[0][ni] + ch[kk]);
    STAGE_B(u1, d1);
    LGKM0();
    PHASE_MFMA(0, b0);
    VMC(2);
    SBAR();

#pragma unroll
    for (int ni = 0; ni < 2; ++ni)
#pragma unroll
      for (int kk = 0; kk < 2; ++kk)
        b1[ni][kk] = *(const bf16x8*)(Bb + bRow[1][ni] + ch[kk]);
    STAGE_A(u2, d2);
    LGKM0();
    PHASE_MFMA(1, b1);
    VMC(4);
    SBAR();
  }

  const int cc = lane & 15;
  const int cr4 = (lane >> 4) * 4;
#pragma unroll
  for (int nq = 0; nq < 2; ++nq)
#pragma unroll
    for (int mi = 0; mi < 4; ++mi)
#pragma unroll
      for (int ni = 0; ni < 2; ++ni)
#pragma unroll
        for (int r = 0; r < 4; ++r) {
          int row = m0 + wr * 64 + mi * 16 + cr4 + r;
          int col = n0 + wc * 64 + nq * 32 + ni * 16 + cc;
          size_t idx = (size_t)row * N + col;
          Yb[idx] = f2bf(acc[nq][mi][ni][r] + bf2f(residb[idx]));
        }
#undef STAGE_A
#undef STAGE_B
#undef PHASE_MFMA
}

// ---------------------------------------------------------------- sliding-window attention (MFMA band)
__global__ __launch_bounds__(256) void attn_win_mfma(const ushort* __restrict__ qkv,
                                                     ushort* __restrict__ msg) {
  __shared__ ushort Ks[80][72];
  __shared__ ushort Vt[64][88];
  __shared__ ushort Ps[4][16][40];

  const int tile = blockIdx.x;
  const int h = blockIdx.y;
  const int b = blockIdx.z;
  const int t0 = tile * 64;
  const size_t rowbase = (size_t)b * SEQ_T;
  const int tid = threadIdx.x;
  const int wave = tid >> 6;
  const int lane = tid & 63;

  for (int chunk = tid; chunk < 1280; chunk += 256) {
    int r = chunk >> 4;
    int c = (chunk & 15) * 8;
    int t = t0 - 16 + r;
    u16x8 u = {0, 0, 0, 0, 0, 0, 0, 0};
    if (t >= 0)
      u = *(const u16x8*)(qkv + (rowbase + t) * 3072 + 1024 + (size_t)h * 128 + c);
    if (c < 64) {
      *(u16x8*)&Ks[r][c] = u;
    } else {
      int d0 = c - 64;
#pragma unroll
      for (int j = 0; j < 8; ++j) Vt[d0 + j][r] = u[j];
    }
  }
  __syncthreads();

  const int fr = lane & 15;
  const int g = lane >> 4;
  const int rbase = wave * 16;

  bf16x8 qa[2];
#pragma unroll
  for (int kk = 0; kk < 2; ++kk)
    qa[kk] = *(const bf16x8*)(qkv + (rowbase + t0 + wave * 16 + fr) * 3072 +
                              (size_t)h * 64 + kk * 32 + g * 8);

  f32x4 sacc[2];
  sacc[0] = (f32x4){0.f, 0.f, 0.f, 0.f};
  sacc[1] = (f32x4){0.f, 0.f, 0.f, 0.f};
#pragma unroll
  for (int kk = 0; kk < 2; ++kk) {
#pragma unroll
    for (int nt = 0; nt < 2; ++nt) {
      bf16x8 kb = *(const bf16x8*)&Ks[rbase + nt * 16 + fr][kk * 32 + g * 8];
      sacc[nt] = __builtin_amdgcn_mfma_f32_16x16x32_bf16(qa[kk], kb, sacc[nt], 0, 0, 0);
    }
  }

#pragma unroll
  for (int nt = 0; nt < 2; ++nt) {
    int tk = t0 - 16 + rbase + nt * 16 + fr;
#pragma unroll
    for (int reg = 0; reg < 4; ++reg) {
      int t = t0 + wave * 16 + g * 4 + reg;
      float tau = 0.f;
      if (tk >= 0 && tk >= t - WIN && tk <= t - 1)
        tau = 1.f / (1.f + __expf(-sacc[nt][reg] * 0.125f));
      Ps[wave][g * 4 + reg][nt * 16 + fr] = f2bf(tau);
    }
  }
  __syncthreads();

  bf16x8 pa = *(const bf16x8*)&Ps[wave][fr][g * 8];
#pragma unroll
  for (int ct = 0; ct < 4; ++ct) {
    bf16x8 vb = *(const bf16x8*)&Vt[ct * 16 + fr][rbase + g * 8];
    f32x4 m = __builtin_amdgcn_mfma_f32_16x16x32_bf16(pa, vb, (f32x4){0.f, 0.f, 0.f, 0.f}, 0, 0, 0);
#pragma unroll
    for (int reg = 0; reg < 4; ++reg) {
      int t = t0 + wave * 16 + g * 4 + reg;
      msg[(rowbase + t) * 1024 + (size_t)h * 64 + ct * 16 + fr] = f2bf(m[reg]);
    }
  }
}

// ---------------------------------------------------------------- LayerNorm: bf16 y in -> fp32 out
__global__ __launch_bounds__(256) void layernorm_b(const ushort* __restrict__ yb,
                                                   const float* __restrict__ gamma,
                                                   const float* __restrict__ beta,
                                                   float* __restrict__ out) {
  const int row = blockIdx.x;
  const ushort* p = yb + (size_t)row * D_MODEL;
  const int tid = threadIdx.x;
  ushort4 v4 = ((const ushort4*)p)[tid];
  float y0 = bf2f(v4.x), y1 = bf2f(v4.y), y2 = bf2f(v4.z), y3 = bf2f(v4.w);
  float s = y0 + y1 + y2 + y3;
  float s2 = y0 * y0 + y1 * y1 + y2 * y2 + y3 * y3;
#pragma unroll
  for (int m = 1; m < 64; m <<= 1) {
    s += __shfl_xor(s, m);
    s2 += __shfl_xor(s2, m);
  }
  __shared__ float red[8];
  const int wave = tid >> 6, lane = tid & 63;
  if (lane == 0) { red[wave] = s; red[4 + wave] = s2; }
  __syncthreads();
  s = red[0] + red[1] + red[2] + red[3];
  s2 = red[4] + red[5] + red[6] + red[7];
  const float mu = s * (1.f / D_MODEL);
  const float var = s2 * (1.f / D_MODEL) - mu * mu;
  const float rstd = rsqrtf(var + 1e-5f);
  float4 g = *(const float4*)&gamma[tid * 4];
  float4 be = *(const float4*)&beta[tid * 4];
  float4 o;
  o.x = (y0 - mu) * rstd * g.x + be.x;
  o.y = (y1 - mu) * rstd * g.y + be.y;
  o.z = (y2 - mu) * rstd * g.z + be.z;
  o.w = (y3 - mu) * rstd * g.w + be.w;
  *(float4*)&out[(size_t)row * D_MODEL + tid * 4] = o;
}

// ---------------------------------------------------------------- launch
extern "C" void kernel_launch(void* const* d_in, const int* in_sizes, int n_in,
                              void* d_out, int out_size, void* d_ws, size_t ws_size,
                              hipStream_t stream) {
  (void)in_sizes; (void)n_in; (void)out_size; (void)ws_size;
  const float* x = (const float*)d_in[0];
  const float* wq = (const float*)d_in[1];
  const float* wkv = (const float*)d_in[2];
  const float* wo = (const float*)d_in[3];
  const float* gamma = (const float*)d_in[4];
  const float* beta = (const float*)d_in[5];
  float* out = (float*)d_out;

  ushort* xb = (ushort*)d_ws;                          // 8192x1024 bf16
  ushort* wb = xb + (size_t)8192 * 1024;               // 4096x1024: [wq;wkv;wo]
  ushort* qkvb = wb + (size_t)4096 * 1024;             // 8192x3072 (dead after attn)
  ushort* msgb = qkvb + (size_t)8192 * 3072;           // 8192x1024
  ushort* yb = qkvb;                                   // aliases qkvb (safe: attn done)

  const int M = NBATCH * SEQ_T;  // 8192

  (void)hipFuncSetAttribute(reinterpret_cast<const void*>(&gemm1_6ph),
                            hipFuncAttributeMaxDynamicSharedMemorySize, 114688);
  (void)hipFuncSetAttribute(reinterpret_cast<const void*>(&gemm2_b),
                            hipFuncAttributeMaxDynamicSharedMemorySize, 98304);

  // casts (x + all weights, one launch)
  cast_all<<<12288, 256, 0, stream>>>((const float4*)x, (const float4*)wq,
                                      (const float4*)wkv, (const float4*)wo, xb, wb);

  // GEMM1: qkv = x @ [wq;wkv]^T  (M=8192, N=3072, K=1024) -> 16x32 = 512 blocks = 2.0 rounds
  gemm1_6ph<<<dim3(3072 / 192, M / 256), 512, 114688, stream>>>(xb, wb, qkvb, M, 3072, 1024);

  // windowed sigmoid attention -> msg (bf16)
  attn_win_mfma<<<dim3(SEQ_T / 64, NHEADS, NBATCH), 256, 0, stream>>>(qkvb, msgb);

  // GEMM2: y = bf16(msg @ wo^T + x)  -> yb (aliases qkvb)
  gemm2_b<<<dim3(1024 / 128, M / 256), 512, 98304, stream>>>(msgb, wb + (size_t)3072 * 1024,
                                                             xb, yb, M, 1024, 1024);

  // LayerNorm: yb (bf16) -> out (fp32)
  layernorm_b<<<M, 256, 0, stream>>>(yb, gamma, beta, out);
}